// Round 18
// baseline (35.698 us; speedup 1.0000x reference)
//
#include <hip/hip_runtime.h>

// SSIM v30: v29 (33.3us: gload_lds quad-buffer, XCD-locality swizzle,
// cvt_pk RNE) + one-step-ahead LDS->register pipelining.
// v29 proved the wall is fill LATENCY (XCD swizzle: FETCH 95->51MB,
// -22% dur). Remaining per-step serial chain: VMW->BAR->ds_read(~120cy
// exposed)->pack->MFMA, x17 steps x3 blocks/SIMD. v30: VMW(6)->VMW(3)
// (chunk c+1 complete at step c; only c+2 in flight) and pre-read chunk
// c+1's 4 float4 fragments into NAMED registers right after BAR, while
// cstep computes on registers read LAST step -> ds_read latency fully
// hidden; cstep touches no LDS. Global cover drops to depth-1 (~1 step
// ~1200cy) -- marginal at pure-HBM (v25, 900cy) but sufficient now that
// ~2/3 of fills are L2-served (~250cy) post-swizzle (regime change).
// Buffer hazard: buf written at step c last pre-read at step c-3; two
// barriers intervene. Math byte-identical (absmax exactly 0.0078125).

typedef __attribute__((ext_vector_type(8))) short bf16x8;
typedef __attribute__((ext_vector_type(4))) float f32x4;
typedef __attribute__((ext_vector_type(2))) float f32x2;
typedef __attribute__((ext_vector_type(2))) __bf16 bfx2;

constexpr int TX   = 64;             // block out-cols (4 waves x 16)
constexpr int BY   = 256;            // block out-rows
constexpr int IMW  = 512;
constexpr int IMH  = 512;
constexpr int NPL  = 48;
constexpr int GX   = IMW / TX;       // 8
constexpr int GYB  = IMH / BY;       // 2
constexpr int NBLK = GX * GYB * NPL; // 768
constexpr int NCH  = BY / 16;        // 16; chunks 0..16
constexpr int CB   = 12288;          // bytes per chunk buffer (768 float4)
constexpr float C1c = 0.01f * 0.01f;
constexpr float C2c = 0.03f * 0.03f;

union frag {
    bf16x8 f;
    unsigned int u[4];
    uint4 q;
};

// RNE f32->bf16 pair pack, software (setup kernel only; bit-identical to HW RNE).
__device__ __forceinline__ unsigned int pk_bf16(float lo, float hi) {
    unsigned int a = __float_as_uint(lo);
    unsigned int b = __float_as_uint(hi);
    a += 0x7FFFu + ((a >> 16) & 1u);
    b += 0x7FFFu + ((b >> 16) & 1u);
    return (b & 0xFFFF0000u) | (a >> 16);
}

// HW RNE pair pack: vector fptrunc -> v_cvt_pk_bf16_f32 (1 VALU op).
__device__ __forceinline__ unsigned int pk_rne(float lo, float hi) {
    f32x2 v; v.x = lo; v.y = hi;
    bfx2 b = __builtin_convertvector(v, bfx2);
    return *reinterpret_cast<unsigned int*>(&b);
}

// Normalized 11-tap Gaussian (sigma=1.5); wt[d] for d in [0,11), else 0.
__device__ __forceinline__ float wsel(int d) {
    float w = 0.f;
    w = (d == 0 || d == 10) ? 0.00102838f : w;
    w = (d == 1 || d == 9)  ? 0.00759876f : w;
    w = (d == 2 || d == 8)  ? 0.03600077f : w;
    w = (d == 3 || d == 7)  ? 0.10936082f : w;
    w = (d == 4 || d == 6)  ? 0.21300553f : w;
    w = (d == 5)            ? 0.26601171f : w;
    return w;
}

// Per-lane weight fragments (8 words/lane):
//   words 0..3: whf  — H-pass B-frag,  W[k][n] = wt[k-n-3],   k = lg*8+j
//   words 4..7: whv  — V-pass A-frag with permuted rows,
//                      W'[k][n] = wt[wr(k)-n-3],
//                      wr(k) = (j<4 ? lg*4+j : 12+lg*4+j), j = k&7
__global__ void ssim_weight_setup(unsigned int* __restrict__ wbuf)
{
    const int lane = threadIdx.x & 63;
    const int ln   = lane & 15;
    const int lg   = lane >> 4;
#pragma unroll
    for (int w = 0; w < 4; ++w) {
        const int ka = lg * 8 + 2 * w;
        wbuf[lane * 8 + w] = pk_bf16(wsel(ka - ln - 3), wsel(ka + 1 - ln - 3));
        const int j0  = 2 * w;
        const int wr0 = (j0 < 4) ? (lg * 4 + j0) : (12 + lg * 4 + j0);
        wbuf[lane * 8 + 4 + w] = pk_bf16(wsel(wr0 - ln - 3), wsel(wr0 + 1 - ln - 3));
    }
}

// H-pass for one chunk from PRE-READ registers (no LDS access): the exact
// v12 fragment floats; zero-predicate, pack (RNE cvt_pk), 5 MFMAs -> D.
__device__ __forceinline__ void cstepR(float4 ra0, float4 ra1,
                                       float4 rb0, float4 rb1, bool ok,
                                       const frag& whf,
                                       uint2* __restrict__ D)
{
    const float4 zz = make_float4(0.f, 0.f, 0.f, 0.f);
    if (!ok) { ra0 = zz; ra1 = zz; rb0 = zz; rb1 = zz; }

    const f32x4 z = {0.f, 0.f, 0.f, 0.f};
    frag fa, fb, faa, fbb, fab;
    fa.u[0]  = pk_rne(ra0.x, ra0.y);               fb.u[0]  = pk_rne(rb0.x, rb0.y);
    faa.u[0] = pk_rne(ra0.x*ra0.x, ra0.y*ra0.y);
    fbb.u[0] = pk_rne(rb0.x*rb0.x, rb0.y*rb0.y);
    fab.u[0] = pk_rne(ra0.x*rb0.x, ra0.y*rb0.y);
    fa.u[1]  = pk_rne(ra0.z, ra0.w);               fb.u[1]  = pk_rne(rb0.z, rb0.w);
    faa.u[1] = pk_rne(ra0.z*ra0.z, ra0.w*ra0.w);
    fbb.u[1] = pk_rne(rb0.z*rb0.z, rb0.w*rb0.w);
    fab.u[1] = pk_rne(ra0.z*rb0.z, ra0.w*rb0.w);
    fa.u[2]  = pk_rne(ra1.x, ra1.y);               fb.u[2]  = pk_rne(rb1.x, rb1.y);
    faa.u[2] = pk_rne(ra1.x*ra1.x, ra1.y*ra1.y);
    fbb.u[2] = pk_rne(rb1.x*rb1.x, rb1.y*rb1.y);
    fab.u[2] = pk_rne(ra1.x*rb1.x, ra1.y*rb1.y);
    fa.u[3]  = pk_rne(ra1.z, ra1.w);               fb.u[3]  = pk_rne(rb1.z, rb1.w);
    faa.u[3] = pk_rne(ra1.z*ra1.z, ra1.w*ra1.w);
    fbb.u[3] = pk_rne(rb1.z*rb1.z, rb1.w*rb1.w);
    fab.u[3] = pk_rne(ra1.z*rb1.z, ra1.w*rb1.w);

    f32x4 d;
    d = __builtin_amdgcn_mfma_f32_16x16x32_bf16(fa.f,  whf.f, z, 0, 0, 0);
    D[0] = make_uint2(pk_rne(d[0], d[1]), pk_rne(d[2], d[3]));
    d = __builtin_amdgcn_mfma_f32_16x16x32_bf16(fb.f,  whf.f, z, 0, 0, 0);
    D[1] = make_uint2(pk_rne(d[0], d[1]), pk_rne(d[2], d[3]));
    d = __builtin_amdgcn_mfma_f32_16x16x32_bf16(faa.f, whf.f, z, 0, 0, 0);
    D[2] = make_uint2(pk_rne(d[0], d[1]), pk_rne(d[2], d[3]));
    d = __builtin_amdgcn_mfma_f32_16x16x32_bf16(fbb.f, whf.f, z, 0, 0, 0);
    D[3] = make_uint2(pk_rne(d[0], d[1]), pk_rne(d[2], d[3]));
    d = __builtin_amdgcn_mfma_f32_16x16x32_bf16(fab.f, whf.f, z, 0, 0, 0);
    D[4] = make_uint2(pk_rne(d[0], d[1]), pk_rne(d[2], d[3]));
}

// V-pass for one 16-row out-tile from D_prev (chunk t) + D_cur (chunk t+1).
__device__ __forceinline__ void vstep(const frag& whv,
                                      const uint2* __restrict__ Dp,
                                      const uint2* __restrict__ Dc,
                                      float& lsum)
{
    const f32x4 z = {0.f, 0.f, 0.f, 0.f};
    f32x4 res[5];
#pragma unroll
    for (int p = 0; p < 5; ++p) {
        frag Bf;
        Bf.u[0] = Dp[p].x; Bf.u[1] = Dp[p].y;
        Bf.u[2] = Dc[p].x; Bf.u[3] = Dc[p].y;
        res[p] = __builtin_amdgcn_mfma_f32_16x16x32_bf16(whv.f, Bf.f, z, 0, 0, 0);
    }
#pragma unroll
    for (int j = 0; j < 4; ++j) {
        const float mu1 = res[0][j];
        const float mu2 = res[1][j];
        const float m1s = mu1 * mu1;
        const float m2s = mu2 * mu2;
        const float m12 = mu1 * mu2;
        const float s11 = res[2][j] - m1s;
        const float s22 = res[3][j] - m2s;
        const float s12 = res[4][j] - m12;
        const float num = (2.f * m12 + C1c) * (2.f * s12 + C2c);
        const float den = (m1s + m2s + C1c) * (s11 + s22 + C2c);
        lsum = fmaf(num, __builtin_amdgcn_rcpf(den), lsum);
    }
}

__global__ __launch_bounds__(256, 3)
void ssim_mfma(const float* __restrict__ img1, const float* __restrict__ img2,
               const unsigned int* __restrict__ wbuf,
               float* __restrict__ partials)
{
    const int tid  = threadIdx.x;
    const int lane = tid & 63;
    const int wave = tid >> 6;        // 0..3
    const int ln   = lane & 15;
    const int lg   = lane >> 4;       // 0..3

    // ---- XCD-locality decode (bijective, 768 = 8 XCDs x 96 slots).
    const int h    = blockIdx.x;
    const int xcd  = h & 7;
    const int slot = h >> 3;              // 0..95
    const int pr   = xcd * 12 + (slot >> 3);   // 0..95 (by,bz) pair
    const int bx   = slot & 7;
    const int by   = pr & 1;
    const int bz   = pr >> 1;

    const int y0   = by * BY;
    const float* __restrict__ p1 = img1 + (size_t)bz * (IMW * IMH);
    const float* __restrict__ p2 = img2 + (size_t)bz * (IMW * IMH);

    frag whf, whv;
    whf.q = reinterpret_cast<const uint4*>(wbuf)[lane * 2];
    whv.q = reinterpret_cast<const uint4*>(wbuf)[lane * 2 + 1];

    __shared__ __align__(16) char lds[4 * CB];     // 4 chunk buffers
    __shared__ float wsum[4];

    // ---- per-thread load-slot constants (3 groups: L = tid, +256, +512).
    const int Lp0 = tid;                       // group0 -> img1
    const int rw0 = Lp0 / 24;
    int sg0 = (Lp0 % 24) - rw0; sg0 += (sg0 < 0) ? 24 : 0;
    int cc0 = bx * TX - 16 + 4 * sg0; cc0 = cc0 < 0 ? 0 : (cc0 > IMW - 4 ? IMW - 4 : cc0);
    const float* gb0 = p1;

    const int L1  = tid + 256;
    const int Lp1 = (L1 < 384) ? L1 : (L1 - 384);
    const int rw1 = Lp1 / 24;
    int sg1 = (Lp1 % 24) - rw1; sg1 += (sg1 < 0) ? 24 : 0;
    int cc1 = bx * TX - 16 + 4 * sg1; cc1 = cc1 < 0 ? 0 : (cc1 > IMW - 4 ? IMW - 4 : cc1);
    const float* gb1 = (L1 < 384) ? p1 : p2;

    const int Lp2 = tid + 512 - 384;           // group2 -> img2
    const int rw2 = Lp2 / 24;
    int sg2 = (Lp2 % 24) - rw2; sg2 += (sg2 < 0) ? 24 : 0;
    int cc2 = bx * TX - 16 + 4 * sg2; cc2 = cc2 < 0 ? 0 : (cc2 > IMW - 4 ? IMW - 4 : cc2);
    const float* gb2 = p2;

    const int wbase = wave * 1024;             // wave-uniform LDS group base

    // ---- fragment read offsets (loop-invariant): row ln, segs s0, s0+1
    const int s0  = 4 * wave + 2 + 2 * lg;
    const int rk0 = (s0 + ln) % 24;
    const int rk1 = (s0 + 1 + ln) % 24;
    const int ro0 = (ln * 24 + rk0) * 16;
    const int ro1 = (ln * 24 + rk1) * 16;
    const int cbase = bx * TX + wave * 16 - 8 + lg * 8;
    const bool colok = ((unsigned)cbase <= (unsigned)(IMW - 8));

    uint2 DA[5], DB[5];
    float4 xA0, xA1, xA2, xA3;     // reg set A (fragment of one chunk)
    float4 xB0, xB1, xB2, xB3;     // reg set B
    float lsum = 0.f;

#define CLMP(r) ((r) < 0 ? 0 : ((r) > IMH - 1 ? IMH - 1 : (r)))
#define ISSUE(c, OFF) do{ \
    const int i0 = CLMP(y0 + 16 * (c) - 8 + rw0); \
    const int i1 = CLMP(y0 + 16 * (c) - 8 + rw1); \
    const int i2 = CLMP(y0 + 16 * (c) - 8 + rw2); \
    __builtin_amdgcn_global_load_lds( \
        (const __attribute__((address_space(1))) void*)(gb0 + (size_t)i0 * IMW + cc0), \
        (__attribute__((address_space(3))) void*)(lds + (OFF) + wbase), 16, 0, 0); \
    __builtin_amdgcn_global_load_lds( \
        (const __attribute__((address_space(1))) void*)(gb1 + (size_t)i1 * IMW + cc1), \
        (__attribute__((address_space(3))) void*)(lds + (OFF) + 4096 + wbase), 16, 0, 0); \
    __builtin_amdgcn_global_load_lds( \
        (const __attribute__((address_space(1))) void*)(gb2 + (size_t)i2 * IMW + cc2), \
        (__attribute__((address_space(3))) void*)(lds + (OFF) + 8192 + wbase), 16, 0, 0); \
    } while (0)
#define VMW(n) do{ \
    asm volatile("s_waitcnt vmcnt(" #n ")" ::: "memory"); \
    __builtin_amdgcn_sched_barrier(0); } while (0)
#define BAR() do{ \
    __builtin_amdgcn_sched_barrier(0); \
    __builtin_amdgcn_s_barrier(); \
    __builtin_amdgcn_sched_barrier(0); } while (0)
#define ROWOK(c) (colok && ((unsigned)(y0 + 16 * (c) - 8 + ln) < (unsigned)IMH))
#define RD(OFF, X0, X1, X2, X3) do{ \
    X0 = *reinterpret_cast<const float4*>(lds + (OFF) + ro0); \
    X1 = *reinterpret_cast<const float4*>(lds + (OFF) + ro1); \
    X2 = *reinterpret_cast<const float4*>(lds + (OFF) + CB / 2 + ro0); \
    X3 = *reinterpret_cast<const float4*>(lds + (OFF) + CB / 2 + ro1); } while (0)

    // ---- prologue: issue chunks 0..2; VMW(3) -> chunks 0,1 complete
    // (chunk2's 3 loads outstanding); pre-read chunks 0 AND 1; H(0).
    ISSUE(0, 0 * CB);
    ISSUE(1, 1 * CB);
    ISSUE(2, 2 * CB);
    VMW(3);
    BAR();
    RD(0 * CB, xA0, xA1, xA2, xA3);        // chunk 0 -> set A
    RD(1 * CB, xB0, xB1, xB2, xB3);        // chunk 1 -> set B
    cstepR(xA0, xA1, xA2, xA3, ROWOK(0), whf, DA);   // H of chunk 0

    // ---- main march: step c: ISSUE(c+2); VMW(3) -> chunk c+1 complete
    // (only c+2 in flight, depth-1); BAR; pre-read chunk c+1 into the
    // free reg set; cstepR on the set read LAST step (chunk c); vstep.
    // Odd c: compute set B, pre-read A; even c: compute A, pre-read B.
    for (int u = 0; u < 3; ++u) {          // c = 4u+1 .. 4u+4  (1..12)
        const int c0 = 4 * u;
        ISSUE(c0 + 3, 3 * CB); VMW(3); BAR();
        RD(2 * CB, xA0, xA1, xA2, xA3);    // chunk c0+2
        cstepR(xB0, xB1, xB2, xB3, ROWOK(c0 + 1), whf, DB);
        vstep(whv, DA, DB, lsum);
        ISSUE(c0 + 4, 0 * CB); VMW(3); BAR();
        RD(3 * CB, xB0, xB1, xB2, xB3);    // chunk c0+3
        cstepR(xA0, xA1, xA2, xA3, ROWOK(c0 + 2), whf, DA);
        vstep(whv, DB, DA, lsum);
        ISSUE(c0 + 5, 1 * CB); VMW(3); BAR();
        RD(0 * CB, xA0, xA1, xA2, xA3);    // chunk c0+4
        cstepR(xB0, xB1, xB2, xB3, ROWOK(c0 + 3), whf, DB);
        vstep(whv, DA, DB, lsum);
        ISSUE(c0 + 6, 2 * CB); VMW(3); BAR();
        RD(1 * CB, xB0, xB1, xB2, xB3);    // chunk c0+5
        cstepR(xA0, xA1, xA2, xA3, ROWOK(c0 + 4), whf, DA);
        vstep(whv, DB, DA, lsum);
    }
    // c = 13: ISSUE(15); chunk 14 complete; pre-read 14; compute 13.
    ISSUE(15, 3 * CB); VMW(3); BAR();
    RD(2 * CB, xA0, xA1, xA2, xA3);        // chunk 14
    cstepR(xB0, xB1, xB2, xB3, ROWOK(13), whf, DB);
    vstep(whv, DA, DB, lsum);
    // c = 14: ISSUE(16); chunk 15 complete; pre-read 15; compute 14.
    ISSUE(16, 0 * CB); VMW(3); BAR();
    RD(3 * CB, xB0, xB1, xB2, xB3);        // chunk 15
    cstepR(xA0, xA1, xA2, xA3, ROWOK(14), whf, DA);
    vstep(whv, DB, DA, lsum);
    // c = 15: chunk 16 complete; pre-read 16; compute 15.
    VMW(0); BAR();
    RD(0 * CB, xA0, xA1, xA2, xA3);        // chunk 16
    cstepR(xB0, xB1, xB2, xB3, ROWOK(15), whf, DB);
    vstep(whv, DA, DB, lsum);
    // c = 16: compute 16 (already in regs).
    cstepR(xA0, xA1, xA2, xA3, ROWOK(16), whf, DA);
    vstep(whv, DB, DA, lsum);
#undef CLMP
#undef ISSUE
#undef VMW
#undef BAR
#undef ROWOK
#undef RD

    // ---- Block reduction -> per-block partial ----
#pragma unroll
    for (int off = 32; off > 0; off >>= 1)
        lsum += __shfl_down(lsum, off, 64);

    if (lane == 0) wsum[wave] = lsum;
    __syncthreads();
    if (tid == 0) {
        float tot = wsum[0] + wsum[1] + wsum[2] + wsum[3];
        const int bid = (bz * GYB + by) * GX + bx;
        partials[bid] = tot;
    }
}

__global__ __launch_bounds__(256)
void ssim_reduce_kernel(const float* __restrict__ partials,
                        float* __restrict__ out)
{
    __shared__ double sm[256];
    double s = 0.0;
    for (int i = threadIdx.x; i < NBLK; i += 256) s += (double)partials[i];
    sm[threadIdx.x] = s;
    __syncthreads();
    for (int stride = 128; stride > 0; stride >>= 1) {
        if (threadIdx.x < stride) sm[threadIdx.x] += sm[threadIdx.x + stride];
        __syncthreads();
    }
    if (threadIdx.x == 0) {
        double mean = sm[0] / (double)((size_t)NPL * IMW * IMH);
        out[0] = (float)(1.0 - mean);
    }
}

extern "C" void kernel_launch(void* const* d_in, const int* in_sizes, int n_in,
                              void* d_out, int out_size, void* d_ws, size_t ws_size,
                              hipStream_t stream)
{
    (void)in_sizes; (void)n_in; (void)out_size; (void)ws_size;
    const float* img1 = (const float*)d_in[0];
    const float* img2 = (const float*)d_in[1];
    float* out = (float*)d_out;

    unsigned int* wbuf = (unsigned int*)d_ws;              // 2 KB weight table
    float* partials = (float*)((char*)d_ws + 4096);        // NBLK floats

    ssim_weight_setup<<<1, 64, 0, stream>>>(wbuf);
    ssim_mfma<<<dim3(NBLK), 256, 0, stream>>>(img1, img2, wbuf, partials);
    ssim_reduce_kernel<<<1, 256, 0, stream>>>(partials, out);
}